// Round 1
// baseline (3007.688 us; speedup 1.0000x reference)
//
#include <hip/hip_runtime.h>
#include <hip/hip_bf16.h>
#include <math.h>

// Problem constants
#define Bb 4
#define Nn 1025
#define Cc 768
#define Hh 12
#define Dh 64
#define BH (Bb*Hh)          // 48
#define M_ROWS (Bb*Nn)      // 4100
#define KSEL 256            // int(1024*0.25)

// ---------------------------------------------------------------------------
// zero scratch accumulators (ws is poisoned 0xAA before every launch)
__global__ void zero_ws(float* colsum, float* cnt) {
    int t = blockIdx.x * 256 + threadIdx.x;
    if (t < BH * Nn) colsum[t] = 0.f;
    if (t < Nn) cnt[t] = 0.f;
}

// ---------------------------------------------------------------------------
// Tiled fp32 GEMM, 64x64 tile, 16x16 threads, 4x4 micro-tile, K-tile 16.
// mode 0: C = A*B, scatter into q [B,H,N,D], kT [B,H,D,N], v [B,H,N,D]
// mode 1: C = A*B + bias, row-major out [M,N]
__global__ __launch_bounds__(256)
void gemm_tiled(const float* __restrict__ A, const float* __restrict__ Bm,
                int M, int K, int N, int mode,
                float* __restrict__ qp, float* __restrict__ kTp, float* __restrict__ vp,
                float* __restrict__ outp, const float* __restrict__ bias)
{
    __shared__ float As[16][68];  // [k][m], padded: 68*4B rows keep 16B align, 2-way max conflict
    __shared__ float Bs[16][68];  // [k][n]
    const int tx = threadIdx.x, ty = threadIdx.y;
    const int tid = ty * 16 + tx;
    const int m0 = blockIdx.x * 64, n0 = blockIdx.y * 64;
    float acc[4][4] = {};

    for (int k0 = 0; k0 < K; k0 += 16) {
#pragma unroll
        for (int i = 0; i < 4; ++i) {
            int L = tid + 256 * i;
            int mm = L >> 4, kk = L & 15;          // A: 64 rows x 16 k
            int gm = m0 + mm;
            As[kk][mm] = (gm < M) ? A[(size_t)gm * K + k0 + kk] : 0.f;
            int kk2 = L >> 6, nn = L & 63;         // B: 16 k x 64 cols (coalesced)
            Bs[kk2][nn] = Bm[(size_t)(k0 + kk2) * N + n0 + nn];
        }
        __syncthreads();
#pragma unroll
        for (int kk = 0; kk < 16; ++kk) {
            float4 a4 = *(const float4*)&As[kk][ty * 4];
            float4 b4 = *(const float4*)&Bs[kk][tx * 4];
            float av[4] = {a4.x, a4.y, a4.z, a4.w};
            float bv[4] = {b4.x, b4.y, b4.z, b4.w};
#pragma unroll
            for (int i2 = 0; i2 < 4; ++i2)
#pragma unroll
                for (int j2 = 0; j2 < 4; ++j2)
                    acc[i2][j2] += av[i2] * bv[j2];
        }
        __syncthreads();
    }

#pragma unroll
    for (int i2 = 0; i2 < 4; ++i2) {
        int gm = m0 + ty * 4 + i2;
        if (gm >= M) continue;
#pragma unroll
        for (int j2 = 0; j2 < 4; ++j2) {
            int o = n0 + tx * 4 + j2;
            float val = acc[i2][j2];
            if (mode == 1) {
                outp[(size_t)gm * N + o] = val + bias[o];
            } else {
                int b = gm / Nn, n = gm % Nn;
                int s = o / Cc, r = o % Cc;
                int h = r >> 6, d = r & 63;
                size_t bh = (size_t)(b * Hh + h);
                if (s == 0)      qp[(bh * Nn + n) * Dh + d] = val;
                else if (s == 1) kTp[(bh * Dh + d) * Nn + n] = val;
                else             vp[(bh * Nn + n) * Dh + d] = val;
            }
        }
    }
}

// ---------------------------------------------------------------------------
// Pass A: per attention row compute softmax stats (m,l) and accumulate
// column-sums of probabilities. One block handles 16 rows of one (b,h).
__global__ __launch_bounds__(256)
void attn_stats(const float* __restrict__ q, const float* __restrict__ kT,
                float* __restrict__ m_out, float* __restrict__ l_out,
                float* __restrict__ colsum)
{
    const int chunk = blockIdx.x % 65;
    const int bh = blockIdx.x / 65;
    const int tid = threadIdx.x;
    __shared__ float qs[64];
    __shared__ float logit[Nn];
    __shared__ float csum[Nn];
    __shared__ float red[256];

    for (int j = tid; j < Nn; j += 256) csum[j] = 0.f;
    const float* kTbh = kT + (size_t)bh * Dh * Nn;
    const int row0 = chunk * 16;

    for (int r = 0; r < 16; ++r) {
        int i = row0 + r;
        if (i >= Nn) break;               // block-uniform
        __syncthreads();                  // protect qs / prior-iter LDS reads
        if (tid < 64) qs[tid] = q[((size_t)bh * Nn + i) * Dh + tid];
        __syncthreads();

        float lmax = -1e30f;
        for (int j = tid; j < Nn; j += 256) {
            float acc = 0.f;
#pragma unroll 8
            for (int d = 0; d < 64; ++d) acc += qs[d] * kTbh[d * Nn + j];
            acc *= 0.125f;
            logit[j] = acc;
            lmax = fmaxf(lmax, acc);
        }
        red[tid] = lmax; __syncthreads();
        for (int s = 128; s > 0; s >>= 1) {
            if (tid < s) red[tid] = fmaxf(red[tid], red[tid + s]);
            __syncthreads();
        }
        float m = red[0];
        __syncthreads();

        float lsum = 0.f;
        for (int j = tid; j < Nn; j += 256) {
            float p = __expf(logit[j] - m);
            logit[j] = p;
            lsum += p;
        }
        red[tid] = lsum; __syncthreads();
        for (int s = 128; s > 0; s >>= 1) {
            if (tid < s) red[tid] += red[tid + s];
            __syncthreads();
        }
        float l = red[0];
        float inv = 1.f / l;
        for (int j = tid; j < Nn; j += 256) csum[j] += logit[j] * inv;
        if (tid == 0) { m_out[bh * Nn + i] = m; l_out[bh * Nn + i] = l; }
    }
    __syncthreads();
    for (int j = tid; j < Nn; j += 256) atomicAdd(&colsum[bh * Nn + j], csum[j]);
}

// ---------------------------------------------------------------------------
// UCB score + exact top-256 (bitonic sort over 1024 (val,idx)) per batch.
// Writes keep[b, 0..1024] and cnt[j] += 1/B for selected tokens.
__global__ __launch_bounds__(1024)
void ucb_topk(const float* __restrict__ colsum, const float* __restrict__ ucb_score,
              const int* __restrict__ counter_p,
              float* __restrict__ keep, float* __restrict__ cnt)
{
    const int b = blockIdx.x;
    const int tid = threadIdx.x;          // 0..1023
    __shared__ float vals[1024];
    __shared__ int   idxs[1024];

    const int j = tid + 1;
    float lc = logf((float)(*counter_p) + 1.0f);
    float s = 0.f;
#pragma unroll
    for (int h = 0; h < Hh; ++h) {
        s += colsum[(b * Hh + h) * Nn + j] * (1.0f / (float)Nn);
        s += sqrtf(lc / (ucb_score[h * Nn + j] + 1e-6f));
    }
    s *= (1.0f / (float)Hh);
    vals[tid] = s; idxs[tid] = tid;
    __syncthreads();

    // bitonic sort, descending by (val, then ascending idx for ties)
    for (int k = 2; k <= 1024; k <<= 1) {
        for (int jj = k >> 1; jj > 0; jj >>= 1) {
            int partner = tid ^ jj;
            if (partner > tid) {
                float v1 = vals[tid], v2 = vals[partner];
                int i1 = idxs[tid], i2 = idxs[partner];
                bool gt = (v1 > v2) || (v1 == v2 && i1 < i2);
                bool desc = ((tid & k) == 0);
                if (desc ? !gt : gt) {
                    vals[tid] = v2; vals[partner] = v1;
                    idxs[tid] = i2; idxs[partner] = i1;
                }
            }
            __syncthreads();
        }
    }

    keep[b * Nn + tid] = 0.f;
    if (tid == 0) keep[b * Nn + 1024] = 0.f;
    __syncthreads();
    if (tid < KSEL) {
        int tok = idxs[tid] + 1;
        keep[b * Nn + tok] = 1.f;
        atomicAdd(&cnt[tok], 1.0f / (float)Bb);
    }
    if (tid == 0) keep[b * Nn + 0] = 1.f;
}

// ---------------------------------------------------------------------------
// score_delta = broadcast cnt over heads
__global__ void write_delta(const float* __restrict__ cnt, float* __restrict__ out2) {
    int t = blockIdx.x * 256 + threadIdx.x;
    if (t < Hh * Nn) out2[t] = cnt[t % Nn];
}

// ---------------------------------------------------------------------------
// Pass B: recompute probs, apply keep mask + renorm, accumulate context.
// One block per attention row. ctx2 written as [B,N,C] for the proj GEMM.
__global__ __launch_bounds__(256)
void attn_ctx(const float* __restrict__ q, const float* __restrict__ kT,
              const float* __restrict__ v,
              const float* __restrict__ m_arr, const float* __restrict__ l_arr,
              const float* __restrict__ keep, float* __restrict__ ctx2)
{
    const int idx = blockIdx.x;
    const int i = idx % Nn;
    const int bh = idx / Nn;
    const int b = bh / Hh, h = bh % Hh;
    const int tid = threadIdx.x;
    __shared__ float qs[64];
    __shared__ float parr[Nn];
    __shared__ float red[256];

    const float* kTbh = kT + (size_t)bh * Dh * Nn;
    const float* vbh  = v  + (size_t)bh * Nn * Dh;
    if (tid < 64) qs[tid] = q[((size_t)bh * Nn + i) * Dh + tid];
    __syncthreads();

    const float m = m_arr[bh * Nn + i];
    const float inv = 1.f / l_arr[bh * Nn + i];
    const float rowkeep = keep[b * Nn + i];
    float dsum = 0.f;
    for (int j = tid; j < Nn; j += 256) {
        float acc = 0.f;
#pragma unroll 8
        for (int d = 0; d < 64; ++d) acc += qs[d] * kTbh[d * Nn + j];
        float p = __expf(acc * 0.125f - m) * inv;
        float w = (rowkeep > 0.5f) ? 1.0f : keep[b * Nn + j];
        p *= w;
        parr[j] = p;
        dsum += p;
    }
    red[tid] = dsum; __syncthreads();
    for (int s = 128; s > 0; s >>= 1) {
        if (tid < s) red[tid] += red[tid + s];
        __syncthreads();
    }
    const float invd = 1.f / (red[0] + 1e-8f);

    // phase 2: 4 j-groups x 64 d-lanes
    const int d = tid & 63, g = tid >> 6;
    float acc = 0.f;
    for (int jj = g; jj < Nn; jj += 4) acc += parr[jj] * vbh[(size_t)jj * Dh + d];
    __syncthreads();
    red[tid] = acc; __syncthreads();
    if (g == 0) {
        float tot = (red[d] + red[64 + d] + red[128 + d] + red[192 + d]) * invd;
        ctx2[((size_t)(b * Nn + i)) * Cc + h * Dh + d] = tot;
    }
}

// ---------------------------------------------------------------------------
extern "C" void kernel_launch(void* const* d_in, const int* in_sizes, int n_in,
                              void* d_out, int out_size, void* d_ws, size_t ws_size,
                              hipStream_t stream) {
    const float* x     = (const float*)d_in[0];
    const float* ucb   = (const float*)d_in[1];
    const float* Wqkv  = (const float*)d_in[2];
    const float* Wproj = (const float*)d_in[3];
    const float* bproj = (const float*)d_in[4];
    const int*   counter = (const int*)d_in[5];
    // d_in[6] = ucb_enabled (path is structurally fixed by output shape)

    float* ws = (float*)d_ws;
    float* q      = ws;                     // [B,H,N,D]  3,148,800
    float* kT     = q      + 3148800;       // [B,H,D,N]  3,148,800
    float* v      = kT     + 3148800;       // [B,H,N,D]  3,148,800
    float* ctx2   = v      + 3148800;       // [B,N,C]    3,148,800
    float* m_arr  = ctx2   + 3148800;       // [B,H,N]    49,200
    float* l_arr  = m_arr  + 49200;
    float* colsum = l_arr  + 49200;         // [B,H,N]
    float* keep   = colsum + 49200;         // [B,N]      4,100
    float* cnt    = keep   + 4100;          // [N]        1,025

    float* out  = (float*)d_out;            // [B,N,C]
    float* out2 = out + 3148800;            // [H,N]

    zero_ws<<<dim3(200), dim3(256), 0, stream>>>(colsum, cnt);
    gemm_tiled<<<dim3(65, 36), dim3(16, 16), 0, stream>>>(
        x, Wqkv, M_ROWS, Cc, 3 * Cc, 0, q, kT, v, nullptr, nullptr);
    attn_stats<<<dim3(BH * 65), dim3(256), 0, stream>>>(q, kT, m_arr, l_arr, colsum);
    ucb_topk<<<dim3(Bb), dim3(1024), 0, stream>>>(colsum, ucb, counter, keep, cnt);
    write_delta<<<dim3(49), dim3(256), 0, stream>>>(cnt, out2);
    attn_ctx<<<dim3(BH * Nn), dim3(256), 0, stream>>>(q, kT, v, m_arr, l_arr, keep, ctx2);
    gemm_tiled<<<dim3(65, 12), dim3(16, 16), 0, stream>>>(
        ctx2, Wproj, M_ROWS, Cc, Cc, 1, nullptr, nullptr, nullptr, out, bproj);
}

// Round 2
// 954.515 us; speedup vs baseline: 3.1510x; 3.1510x over previous
//
#include <hip/hip_runtime.h>
#include <hip/hip_bf16.h>
#include <math.h>

// Problem constants
#define Bb 4
#define Nn 1025
#define Cc 768
#define Hh 12
#define Dh 64
#define BH (Bb*Hh)          // 48
#define M_ROWS (Bb*Nn)      // 4100
#define KSEL 256            // int(1024*0.25)
#define KSTRIDE 1028        // padded kT row stride (16B-aligned rows)
#define NJT 17              // ceil(1025/64)

// ---------------------------------------------------------------------------
__global__ void zero_ws(float* colsum_b, float* cnt) {
    int t = blockIdx.x * 256 + threadIdx.x;
    if (t < Bb * Nn) colsum_b[t] = 0.f;
    if (t < Nn) cnt[t] = 0.f;
}

// ---------------------------------------------------------------------------
// Tiled fp32 GEMM, 64x64 tile, 16x16 threads, 4x4 micro-tile, K-tile 16.
// mode 0: C = A*B, scatter into q [B,H,N,D], kT [B,H,D,N(pad 1028)], v [B,H,N,D]
// mode 1: C = A*B + bias, row-major out [M,N]
__global__ __launch_bounds__(256)
void gemm_tiled(const float* __restrict__ A, const float* __restrict__ Bm,
                int M, int K, int N, int mode,
                float* __restrict__ qp, float* __restrict__ kTp, float* __restrict__ vp,
                float* __restrict__ outp, const float* __restrict__ bias)
{
    __shared__ float As[16][68];
    __shared__ float Bs[16][68];
    const int tx = threadIdx.x, ty = threadIdx.y;
    const int tid = ty * 16 + tx;
    const int m0 = blockIdx.x * 64, n0 = blockIdx.y * 64;
    float acc[4][4] = {};

    for (int k0 = 0; k0 < K; k0 += 16) {
#pragma unroll
        for (int i = 0; i < 4; ++i) {
            int L = tid + 256 * i;
            int mm = L >> 4, kk = L & 15;
            int gm = m0 + mm;
            As[kk][mm] = (gm < M) ? A[(size_t)gm * K + k0 + kk] : 0.f;
            int kk2 = L >> 6, nn = L & 63;
            Bs[kk2][nn] = Bm[(size_t)(k0 + kk2) * N + n0 + nn];
        }
        __syncthreads();
#pragma unroll
        for (int kk = 0; kk < 16; ++kk) {
            float4 a4 = *(const float4*)&As[kk][ty * 4];
            float4 b4 = *(const float4*)&Bs[kk][tx * 4];
            float av[4] = {a4.x, a4.y, a4.z, a4.w};
            float bv[4] = {b4.x, b4.y, b4.z, b4.w};
#pragma unroll
            for (int i2 = 0; i2 < 4; ++i2)
#pragma unroll
                for (int j2 = 0; j2 < 4; ++j2)
                    acc[i2][j2] += av[i2] * bv[j2];
        }
        __syncthreads();
    }

#pragma unroll
    for (int i2 = 0; i2 < 4; ++i2) {
        int gm = m0 + ty * 4 + i2;
        if (gm >= M) continue;
#pragma unroll
        for (int j2 = 0; j2 < 4; ++j2) {
            int o = n0 + tx * 4 + j2;
            float val = acc[i2][j2];
            if (mode == 1) {
                outp[(size_t)gm * N + o] = val + bias[o];
            } else {
                int b = gm / Nn, n = gm % Nn;
                int s = o / Cc, r = o % Cc;
                int h = r >> 6, d = r & 63;
                size_t bh = (size_t)(b * Hh + h);
                if (s == 0)      qp[(bh * Nn + n) * Dh + d] = val;
                else if (s == 1) kTp[(bh * Dh + d) * KSTRIDE + n] = val;
                else             vp[(bh * Nn + n) * Dh + d] = val;
            }
        }
    }
}

// ---------------------------------------------------------------------------
// Pass A: column sums of softmax probs, summed over heads into colsum_b[b][j].
// Block: 64 query rows of one (b,h). Two sweeps: (1) row sums l_i,
// (2) colsum_j += exp(s_ij)/l_i. No max-subtraction (|s| < ~6, fp32-safe).
__global__ __launch_bounds__(256)
void attn_colsum(const float* __restrict__ q, const float* __restrict__ kT,
                 float* __restrict__ colsum_b)
{
    __shared__ float Qt[64][68];
    __shared__ float Kt[64][68];
    __shared__ float csum[Nn];
    __shared__ float redA[64][17];
    __shared__ float redB[16][68];
    __shared__ float linv_s[64];

    const int it = blockIdx.x % NJT;
    const int bh = blockIdx.x / NJT;
    const int b  = bh / Hh;
    const int i0 = it * 64;
    const int tid = threadIdx.x;
    const int tx = tid & 15, ty = tid >> 4;

    // stage Qt[d][i] = q[bh,i0+i,d] * 0.125 (transposed, pre-scaled)
#pragma unroll
    for (int r = 0; r < 4; ++r) {
        int idx = tid + 256 * r;
        int i = idx & 63, c = idx >> 6;
        float4 qv = {0.f, 0.f, 0.f, 0.f};
        if (i0 + i < Nn)
            qv = *(const float4*)&q[((size_t)bh * Nn + i0 + i) * Dh + c * 4];
        Qt[c*4+0][i] = qv.x * 0.125f;
        Qt[c*4+1][i] = qv.y * 0.125f;
        Qt[c*4+2][i] = qv.z * 0.125f;
        Qt[c*4+3][i] = qv.w * 0.125f;
    }
    for (int j = tid; j < Nn; j += 256) csum[j] = 0.f;

    float le[4] = {0.f, 0.f, 0.f, 0.f};

    for (int sweep = 0; sweep < 2; ++sweep) {
        for (int jt = 0; jt < NJT; ++jt) {
            const int j0 = jt * 64;
            __syncthreads();
            // stage Kt[d][j] from kT (padded rows -> aligned float4; cols >=Nn
            // hold garbage, masked below)
#pragma unroll
            for (int r = 0; r < 4; ++r) {
                int idx = tid + 256 * r;
                int d = idx >> 4, c = idx & 15;
                float4 kv = *(const float4*)&kT[((size_t)bh * Dh + d) * KSTRIDE + j0 + c * 4];
                *(float4*)&Kt[d][c * 4] = kv;
            }
            __syncthreads();

            float acc[4][4] = {};
#pragma unroll 8
            for (int d = 0; d < 64; ++d) {
                float4 a4 = *(const float4*)&Qt[d][ty * 4];
                float4 b4 = *(const float4*)&Kt[d][tx * 4];
                float av[4] = {a4.x, a4.y, a4.z, a4.w};
                float bv[4] = {b4.x, b4.y, b4.z, b4.w};
#pragma unroll
                for (int ii = 0; ii < 4; ++ii)
#pragma unroll
                    for (int jj = 0; jj < 4; ++jj)
                        acc[ii][jj] += av[ii] * bv[jj];
            }

            if (sweep == 0) {
#pragma unroll
                for (int jj = 0; jj < 4; ++jj) {
                    int j = j0 + tx * 4 + jj;
                    if (j < Nn) {
#pragma unroll
                        for (int ii = 0; ii < 4; ++ii)
                            le[ii] += __expf(acc[ii][jj]);
                    }
                }
            } else {
#pragma unroll
                for (int jj = 0; jj < 4; ++jj) {
                    float pj = 0.f;
                    int j = j0 + tx * 4 + jj;
                    if (j < Nn) {
#pragma unroll
                        for (int ii = 0; ii < 4; ++ii)
                            pj += __expf(acc[ii][jj]) * linv_s[ty * 4 + ii];
                    }
                    redB[ty][tx * 4 + jj] = pj;   // note: overwritten per ty? no: [ty][j]
                }
                __syncthreads();
                if (tid < 64 && j0 + tid < Nn) {
                    float s = 0.f;
#pragma unroll
                    for (int t = 0; t < 16; ++t) s += redB[t][tid];
                    csum[j0 + tid] += s;
                }
            }
        }
        if (sweep == 0) {
            __syncthreads();
#pragma unroll
            for (int ii = 0; ii < 4; ++ii) redA[ty * 4 + ii][tx] = le[ii];
            __syncthreads();
            if (tid < 64) {
                float s = 0.f;
#pragma unroll
                for (int t = 0; t < 16; ++t) s += redA[tid][t];
                linv_s[tid] = (i0 + tid < Nn) ? 1.f / s : 0.f;
            }
        }
    }
    __syncthreads();
    for (int j = tid; j < Nn; j += 256) atomicAdd(&colsum_b[b * Nn + j], csum[j]);
}

// ---------------------------------------------------------------------------
// UCB score + exact top-256 per batch (bitonic over 1024).
__global__ __launch_bounds__(1024)
void ucb_topk(const float* __restrict__ colsum_b, const float* __restrict__ ucb_score,
              const int* __restrict__ counter_p,
              float* __restrict__ keep, float* __restrict__ cnt)
{
    const int b = blockIdx.x;
    const int tid = threadIdx.x;
    __shared__ float vals[1024];
    __shared__ int   idxs[1024];

    const int j = tid + 1;
    float lc = logf((float)(*counter_p) + 1.0f);
    float s = colsum_b[b * Nn + j] * (1.0f / (float)Nn);
#pragma unroll
    for (int h = 0; h < Hh; ++h)
        s += sqrtf(lc / (ucb_score[h * Nn + j] + 1e-6f));
    s *= (1.0f / (float)Hh);
    vals[tid] = s; idxs[tid] = tid;
    __syncthreads();

    for (int k = 2; k <= 1024; k <<= 1) {
        for (int jj = k >> 1; jj > 0; jj >>= 1) {
            int partner = tid ^ jj;
            if (partner > tid) {
                float v1 = vals[tid], v2 = vals[partner];
                int i1 = idxs[tid], i2 = idxs[partner];
                bool gt = (v1 > v2) || (v1 == v2 && i1 < i2);
                bool desc = ((tid & k) == 0);
                if (desc ? !gt : gt) {
                    vals[tid] = v2; vals[partner] = v1;
                    idxs[tid] = i2; idxs[partner] = i1;
                }
            }
            __syncthreads();
        }
    }

    keep[b * Nn + tid] = 0.f;
    if (tid == 0) keep[b * Nn + 1024] = 0.f;
    __syncthreads();
    if (tid < KSEL) {
        int tok = idxs[tid] + 1;
        keep[b * Nn + tok] = 1.f;
        atomicAdd(&cnt[tok], 1.0f / (float)Bb);
    }
    if (tid == 0) keep[b * Nn + 0] = 1.f;
}

// ---------------------------------------------------------------------------
__global__ void write_delta(const float* __restrict__ cnt, float* __restrict__ out2) {
    int t = blockIdx.x * 256 + threadIdx.x;
    if (t < Hh * Nn) out2[t] = cnt[t % Nn];
}

// ---------------------------------------------------------------------------
// Pass B: masked renormalized attention context. Block: 64 rows of one (b,h).
// Normalizer trick: per-row softmax 1/l cancels in sum(p*w*v)/(sum(p*w)+eps),
// so we use unnormalized p = exp(s). eps perturbation ~1e-5 relative.
__global__ __launch_bounds__(256)
void attn_ctx2(const float* __restrict__ q, const float* __restrict__ kT,
               const float* __restrict__ v, const float* __restrict__ keep,
               float* __restrict__ ctx2)
{
    __shared__ float Qt[64][68];
    __shared__ float Kt[64][68];
    __shared__ float Vt[64][68];
    __shared__ float Ps[64][68];
    __shared__ float redA[64][17];
    __shared__ float dinv_s[64];
    __shared__ float keepi[64];
    __shared__ float keepj[64];

    const int it = blockIdx.x % NJT;
    const int bh = blockIdx.x / NJT;
    const int b  = bh / Hh, h = bh % Hh;
    const int i0 = it * 64;
    const int tid = threadIdx.x;
    const int tx = tid & 15, ty = tid >> 4;

#pragma unroll
    for (int r = 0; r < 4; ++r) {
        int idx = tid + 256 * r;
        int i = idx & 63, c = idx >> 6;
        float4 qv = {0.f, 0.f, 0.f, 0.f};
        if (i0 + i < Nn)
            qv = *(const float4*)&q[((size_t)bh * Nn + i0 + i) * Dh + c * 4];
        Qt[c*4+0][i] = qv.x * 0.125f;
        Qt[c*4+1][i] = qv.y * 0.125f;
        Qt[c*4+2][i] = qv.z * 0.125f;
        Qt[c*4+3][i] = qv.w * 0.125f;
    }
    if (tid < 64) keepi[tid] = (i0 + tid < Nn) ? keep[b * Nn + i0 + tid] : 0.f;

    float ds[4] = {0.f, 0.f, 0.f, 0.f};
    float ctx[4][4] = {};

    for (int jt = 0; jt < NJT; ++jt) {
        const int j0 = jt * 64;
        __syncthreads();
#pragma unroll
        for (int r = 0; r < 4; ++r) {
            int idx = tid + 256 * r;
            int d = idx >> 4, c = idx & 15;
            float4 kv = *(const float4*)&kT[((size_t)bh * Dh + d) * KSTRIDE + j0 + c * 4];
            *(float4*)&Kt[d][c * 4] = kv;
            // Vt[j][d]
            int jl = idx >> 4;
            float4 vv = {0.f, 0.f, 0.f, 0.f};
            if (j0 + jl < Nn)
                vv = *(const float4*)&v[((size_t)bh * Nn + j0 + jl) * Dh + c * 4];
            *(float4*)&Vt[jl][c * 4] = vv;
        }
        if (tid < 64) keepj[tid] = (j0 + tid < Nn) ? keep[b * Nn + j0 + tid] : 0.f;
        __syncthreads();

        float acc[4][4] = {};
#pragma unroll 8
        for (int d = 0; d < 64; ++d) {
            float4 a4 = *(const float4*)&Qt[d][ty * 4];
            float4 b4 = *(const float4*)&Kt[d][tx * 4];
            float av[4] = {a4.x, a4.y, a4.z, a4.w};
            float bv[4] = {b4.x, b4.y, b4.z, b4.w};
#pragma unroll
            for (int ii = 0; ii < 4; ++ii)
#pragma unroll
                for (int jj = 0; jj < 4; ++jj)
                    acc[ii][jj] += av[ii] * bv[jj];
        }

#pragma unroll
        for (int jj = 0; jj < 4; ++jj) {
            int j = j0 + tx * 4 + jj;
            float kj = keepj[tx * 4 + jj];
#pragma unroll
            for (int ii = 0; ii < 4; ++ii) {
                float w = (keepi[ty * 4 + ii] > 0.5f) ? 1.f : kj;
                float p = (j < Nn) ? __expf(acc[ii][jj]) * w : 0.f;
                Ps[tx * 4 + jj][ty * 4 + ii] = p;   // transposed: Ps[j][i]
                ds[ii] += p;
            }
        }
        __syncthreads();

        // PV: ctx[ii][dd] += sum_jj Ps[jj][i] * Vt[jj][d]
#pragma unroll 8
        for (int jj = 0; jj < 64; ++jj) {
            float4 p4 = *(const float4*)&Ps[jj][ty * 4];
            float4 v4 = *(const float4*)&Vt[jj][tx * 4];
            float pv[4] = {p4.x, p4.y, p4.z, p4.w};
            float vv[4] = {v4.x, v4.y, v4.z, v4.w};
#pragma unroll
            for (int ii = 0; ii < 4; ++ii)
#pragma unroll
                for (int dd = 0; dd < 4; ++dd)
                    ctx[ii][dd] += pv[ii] * vv[dd];
        }
    }

    __syncthreads();
#pragma unroll
    for (int ii = 0; ii < 4; ++ii) redA[ty * 4 + ii][tx] = ds[ii];
    __syncthreads();
    if (tid < 64) {
        float s = 0.f;
#pragma unroll
        for (int t = 0; t < 16; ++t) s += redA[tid][t];
        dinv_s[tid] = 1.f / (s + 1e-8f);
    }
    __syncthreads();

#pragma unroll
    for (int ii = 0; ii < 4; ++ii) {
        int gi = i0 + ty * 4 + ii;
        if (gi < Nn) {
            float dv = dinv_s[ty * 4 + ii];
            float4 o = {ctx[ii][0] * dv, ctx[ii][1] * dv, ctx[ii][2] * dv, ctx[ii][3] * dv};
            *(float4*)&ctx2[((size_t)(b * Nn + gi)) * Cc + h * Dh + tx * 4] = o;
        }
    }
}

// ---------------------------------------------------------------------------
extern "C" void kernel_launch(void* const* d_in, const int* in_sizes, int n_in,
                              void* d_out, int out_size, void* d_ws, size_t ws_size,
                              hipStream_t stream) {
    const float* x     = (const float*)d_in[0];
    const float* ucb   = (const float*)d_in[1];
    const float* Wqkv  = (const float*)d_in[2];
    const float* Wproj = (const float*)d_in[3];
    const float* bproj = (const float*)d_in[4];
    const int*   counter = (const int*)d_in[5];

    float* ws = (float*)d_ws;
    float* q        = ws;                    // [B,H,N,D]     3,148,800
    float* kT       = q   + 3148800;         // [B,H,D,1028]  3,158,016
    float* v        = kT  + 3158016;         // [B,H,N,D]     3,148,800
    float* ctx2     = v   + 3148800;         // [B,N,C]       3,148,800
    float* colsum_b = ctx2 + 3148800;        // [B,N]         4,100
    float* keep     = colsum_b + 4100;       // [B,N]         4,100
    float* cnt      = keep + 4100;           // [N]           1,025

    float* out  = (float*)d_out;             // [B,N,C]
    float* out2 = out + 3148800;             // [H,N]

    zero_ws<<<dim3(17), dim3(256), 0, stream>>>(colsum_b, cnt);
    gemm_tiled<<<dim3(65, 36), dim3(16, 16), 0, stream>>>(
        x, Wqkv, M_ROWS, Cc, 3 * Cc, 0, q, kT, v, nullptr, nullptr);
    attn_colsum<<<dim3(BH * NJT), dim3(256), 0, stream>>>(q, kT, colsum_b);
    ucb_topk<<<dim3(Bb), dim3(1024), 0, stream>>>(colsum_b, ucb, counter, keep, cnt);
    write_delta<<<dim3(49), dim3(256), 0, stream>>>(cnt, out2);
    attn_ctx2<<<dim3(BH * NJT), dim3(256), 0, stream>>>(q, kT, v, keep, ctx2);
    gemm_tiled<<<dim3(65, 12), dim3(16, 16), 0, stream>>>(
        ctx2, Wproj, M_ROWS, Cc, Cc, 1, nullptr, nullptr, nullptr, out, bproj);
}

// Round 3
// 512.453 us; speedup vs baseline: 5.8692x; 1.8626x over previous
//
#include <hip/hip_runtime.h>
#include <hip/hip_bf16.h>
#include <math.h>

// Problem constants
#define Bb 4
#define Nn 1025
#define Cc 768
#define Hh 12
#define BH (Bb*Hh)          // 48
#define M_ROWS (Bb*Nn)      // 4100
#define KSEL 256            // int(1024*0.25)
#define JP 1152             // padded j (9 sweeps x 128)
#define IT_TILES 68         // qB i-tiles of 16 (i < 1088)
#define NIB 17              // i-blocks of 64
#define NSW 9               // j-sweeps of 128

typedef __attribute__((ext_vector_type(8))) short short8;
typedef __attribute__((ext_vector_type(4))) float floatx4;

static __device__ inline unsigned short f2bf(float v) {       // RNE
    __hip_bfloat16 b = __float2bfloat16(v);
    return *reinterpret_cast<unsigned short*>(&b);
}
static __device__ inline unsigned short tbf(float f) {        // truncate (fast)
    union { float f; unsigned u; } x; x.f = f;
    return (unsigned short)(x.u >> 16);
}

// ---------------------------------------------------------------------------
// zero bf16 buffers (pads must be 0, ws is poisoned 0xAA) + flag buffers
__global__ void zero_ws(unsigned int* p, int n) {
    for (int i = blockIdx.x * 256 + threadIdx.x; i < n; i += gridDim.x * 256)
        p[i] = 0u;
}

// ---------------------------------------------------------------------------
// Tiled fp32 GEMM, 64x64 tile, 16x16 threads, 4x4 micro-tile, K-tile 16.
// mode 0: C = A*B, scatter bf16 into qB (frag-swizzled, x0.125), kR, vT
// mode 1: C = A*B + bias, row-major fp32 out [M,N]
__global__ __launch_bounds__(256)
void gemm_tiled(const float* __restrict__ A, const float* __restrict__ Bm,
                int M, int K, int N, int mode,
                unsigned short* __restrict__ qB, unsigned short* __restrict__ kR,
                unsigned short* __restrict__ vT,
                float* __restrict__ outp, const float* __restrict__ bias)
{
    __shared__ float As[16][68];
    __shared__ float Bs[16][68];
    const int tx = threadIdx.x, ty = threadIdx.y;
    const int tid = ty * 16 + tx;
    const int m0 = blockIdx.x * 64, n0 = blockIdx.y * 64;
    float acc[4][4] = {};

    for (int k0 = 0; k0 < K; k0 += 16) {
#pragma unroll
        for (int i = 0; i < 4; ++i) {
            int L = tid + 256 * i;
            int mm = L >> 4, kk = L & 15;
            int gm = m0 + mm;
            As[kk][mm] = (gm < M) ? A[(size_t)gm * K + k0 + kk] : 0.f;
            int kk2 = L >> 6, nn = L & 63;
            Bs[kk2][nn] = Bm[(size_t)(k0 + kk2) * N + n0 + nn];
        }
        __syncthreads();
#pragma unroll
        for (int kk = 0; kk < 16; ++kk) {
            float4 a4 = *(const float4*)&As[kk][ty * 4];
            float4 b4 = *(const float4*)&Bs[kk][tx * 4];
            float av[4] = {a4.x, a4.y, a4.z, a4.w};
            float bv[4] = {b4.x, b4.y, b4.z, b4.w};
#pragma unroll
            for (int i2 = 0; i2 < 4; ++i2)
#pragma unroll
                for (int j2 = 0; j2 < 4; ++j2)
                    acc[i2][j2] += av[i2] * bv[j2];
        }
        __syncthreads();
    }

#pragma unroll
    for (int i2 = 0; i2 < 4; ++i2) {
        int gm = m0 + ty * 4 + i2;
        if (gm >= M) continue;
#pragma unroll
        for (int j2 = 0; j2 < 4; ++j2) {
            int o = n0 + tx * 4 + j2;
            float val = acc[i2][j2];
            if (mode == 1) {
                outp[(size_t)gm * N + o] = val + bias[o];
            } else {
                int b = gm / Nn, n = gm % Nn;
                int s = o / Cc, r = o % Cc;
                int h = r >> 6, d = r & 63;
                int bh = b * Hh + h;
                if (s == 0) {
                    // B-operand fragment swizzle: lane = q*16 + (n&15), elem d&7
                    int idx = (((bh * IT_TILES + (n >> 4)) * 2 + (d >> 5)) * 512)
                              + ((((d & 31) >> 3) * 16 + (n & 15)) * 8) + (d & 7);
                    qB[idx] = f2bf(val * 0.125f);
                } else if (s == 1) {
                    kR[((size_t)bh * JP + n) * 64 + d] = f2bf(val);
                } else {
                    vT[((size_t)bh * 64 + d) * JP + n] = f2bf(val);
                }
            }
        }
    }
}

// ---------------------------------------------------------------------------
// Pass A (MFMA): colsum_b[b][j] += sum_h sum_i exp(s_ij)/l_i
// Block: 64 q-rows of one (b,h). Two passes over j (row sums l, then colsum).
__global__ __launch_bounds__(256, 2)
void attn_colsum_mfma(const unsigned short* __restrict__ qB,
                      const unsigned short* __restrict__ kR,
                      float* __restrict__ colsum_b)
{
    __shared__ unsigned short kst[128 * 64];   // [j][d-chunk swizzled]
    __shared__ float scratch[4][32][17];
    __shared__ float red16[16][64];
    __shared__ float linv[64];

    const int blk = blockIdx.x;
    const int ib = blk % NIB;
    const int bh = blk / NIB;
    const int b = bh / Hh;
    const int tid = threadIdx.x;
    const int ws = tid >> 6;
    const int ln = tid & 63;
    const int i16 = ln & 15, q = ln >> 4;

    short8 Qf[4][2];
#pragma unroll
    for (int it = 0; it < 4; ++it)
#pragma unroll
        for (int kc = 0; kc < 2; ++kc)
            Qf[it][kc] = *(const short8*)&qB[(((size_t)bh * IT_TILES + ib * 4 + it) * 2 + kc) * 512 + ln * 8];

    float lacc[4] = {0.f, 0.f, 0.f, 0.f};

    // ---- pass 0: row sums ----
    for (int sw = 0; sw < NSW; ++sw) {
        const int j0 = sw * 128;
        __syncthreads();
#pragma unroll
        for (int r = 0; r < 4; ++r) {
            int id = tid + 256 * r;
            int j = id >> 3, cc = id & 7;
            *(uint4*)&kst[j * 64 + ((cc ^ (j & 7)) * 8)] =
                *(const uint4*)&kR[((size_t)bh * JP + j0 + j) * 64 + cc * 8];
        }
        __syncthreads();

        short8 Kf[2][2];
#pragma unroll
        for (int jt = 0; jt < 2; ++jt)
#pragma unroll
            for (int kc = 0; kc < 2; ++kc) {
                int jloc = ws * 32 + jt * 16 + i16;
                Kf[jt][kc] = *(const short8*)&kst[jloc * 64 + (((kc * 4 + q) ^ (jloc & 7)) * 8)];
            }

        floatx4 S[4][2];
#pragma unroll
        for (int it = 0; it < 4; ++it)
#pragma unroll
            for (int jt = 0; jt < 2; ++jt) {
                S[it][jt] = (floatx4){0.f, 0.f, 0.f, 0.f};
#pragma unroll
                for (int kc = 0; kc < 2; ++kc)
                    S[it][jt] = __builtin_amdgcn_mfma_f32_16x16x32_bf16(Kf[jt][kc], Qf[it][kc], S[it][jt], 0, 0, 0);
            }

#pragma unroll
        for (int jt = 0; jt < 2; ++jt)
#pragma unroll
            for (int r = 0; r < 4; ++r) {
                int jj = j0 + ws * 32 + jt * 16 + q * 4 + r;
                float vld = (jj < Nn) ? 1.f : 0.f;
#pragma unroll
                for (int it = 0; it < 4; ++it)
                    lacc[it] += __expf(S[it][jt][r]) * vld;
            }
    }

    __syncthreads();
#pragma unroll
    for (int it = 0; it < 4; ++it) red16[ws * 4 + q][it * 16 + i16] = lacc[it];
    __syncthreads();
    if (tid < 64) {
        float s = 0.f;
#pragma unroll
        for (int t = 0; t < 16; ++t) s += red16[t][tid];
        int gi = ib * 64 + tid;
        linv[tid] = (gi < Nn) ? 1.f / s : 0.f;
    }
    __syncthreads();
    float lw[4];
#pragma unroll
    for (int it = 0; it < 4; ++it) lw[it] = linv[it * 16 + i16];

    // ---- pass 1: column sums ----
    for (int sw = 0; sw < NSW; ++sw) {
        const int j0 = sw * 128;
        __syncthreads();
#pragma unroll
        for (int r = 0; r < 4; ++r) {
            int id = tid + 256 * r;
            int j = id >> 3, cc = id & 7;
            *(uint4*)&kst[j * 64 + ((cc ^ (j & 7)) * 8)] =
                *(const uint4*)&kR[((size_t)bh * JP + j0 + j) * 64 + cc * 8];
        }
        __syncthreads();

        short8 Kf[2][2];
#pragma unroll
        for (int jt = 0; jt < 2; ++jt)
#pragma unroll
            for (int kc = 0; kc < 2; ++kc) {
                int jloc = ws * 32 + jt * 16 + i16;
                Kf[jt][kc] = *(const short8*)&kst[jloc * 64 + (((kc * 4 + q) ^ (jloc & 7)) * 8)];
            }

        floatx4 S[4][2];
#pragma unroll
        for (int it = 0; it < 4; ++it)
#pragma unroll
            for (int jt = 0; jt < 2; ++jt) {
                S[it][jt] = (floatx4){0.f, 0.f, 0.f, 0.f};
#pragma unroll
                for (int kc = 0; kc < 2; ++kc)
                    S[it][jt] = __builtin_amdgcn_mfma_f32_16x16x32_bf16(Kf[jt][kc], Qf[it][kc], S[it][jt], 0, 0, 0);
            }

        float pj[2][4];
#pragma unroll
        for (int jt = 0; jt < 2; ++jt)
#pragma unroll
            for (int r = 0; r < 4; ++r) {
                int jj = j0 + ws * 32 + jt * 16 + q * 4 + r;
                float vld = (jj < Nn) ? 1.f : 0.f;
                float s = 0.f;
#pragma unroll
                for (int it = 0; it < 4; ++it)
                    s += __expf(S[it][jt][r]) * lw[it];
                pj[jt][r] = s * vld;
            }
#pragma unroll
        for (int jt = 0; jt < 2; ++jt)
#pragma unroll
            for (int r = 0; r < 4; ++r)
                scratch[ws][jt * 16 + q * 4 + r][i16] = pj[jt][r];
        __syncthreads();
        if (tid < 128) {
            int wr = tid >> 5, jl = tid & 31;
            float s = 0.f;
#pragma unroll
            for (int t = 0; t < 16; ++t) s += scratch[wr][jl][t];
            atomicAdd(&colsum_b[b * JP + j0 + wr * 32 + jl], s);
        }
    }
}

// ---------------------------------------------------------------------------
// UCB score + exact top-256 per batch (bitonic over 1024).
__global__ __launch_bounds__(1024)
void ucb_topk(const float* __restrict__ colsum_b, const float* __restrict__ ucb_score,
              const int* __restrict__ counter_p,
              float* __restrict__ keepP, float* __restrict__ cnt)
{
    const int b = blockIdx.x;
    const int tid = threadIdx.x;
    __shared__ float vals[1024];
    __shared__ int   idxs[1024];

    const int j = tid + 1;
    float lc = logf((float)(*counter_p) + 1.0f);
    float s = colsum_b[b * JP + j] * (1.0f / (float)Nn);
#pragma unroll
    for (int h = 0; h < Hh; ++h)
        s += sqrtf(lc / (ucb_score[h * Nn + j] + 1e-6f));
    s *= (1.0f / (float)Hh);
    vals[tid] = s; idxs[tid] = tid;
    __syncthreads();

    for (int k = 2; k <= 1024; k <<= 1) {
        for (int jj = k >> 1; jj > 0; jj >>= 1) {
            int partner = tid ^ jj;
            if (partner > tid) {
                float v1 = vals[tid], v2 = vals[partner];
                int i1 = idxs[tid], i2 = idxs[partner];
                bool gt = (v1 > v2) || (v1 == v2 && i1 < i2);
                bool desc = ((tid & k) == 0);
                if (desc ? !gt : gt) {
                    vals[tid] = v2; vals[partner] = v1;
                    idxs[tid] = i2; idxs[partner] = i1;
                }
            }
            __syncthreads();
        }
    }

    if (tid < KSEL) {
        int tok = idxs[tid] + 1;
        keepP[b * JP + tok] = 1.f;
        atomicAdd(&cnt[tok], 1.0f / (float)Bb);
    }
    if (tid == 0) keepP[b * JP + 0] = 1.f;
}

// ---------------------------------------------------------------------------
__global__ void write_delta(const float* __restrict__ cnt, float* __restrict__ out2) {
    int t = blockIdx.x * 256 + threadIdx.x;
    if (t < Hh * Nn) out2[t] = cnt[t % Nn];
}

// ---------------------------------------------------------------------------
// Pass B (MFMA): masked renormalized context.  S^T = K*Q^T -> exp*mask -> P
// (bf16, LDS b64-packed) -> PV via MFMA.  Per-row 1/l cancels in the ratio.
__global__ __launch_bounds__(256, 2)
void attn_ctx_mfma(const unsigned short* __restrict__ qB,
                   const unsigned short* __restrict__ kR,
                   const unsigned short* __restrict__ vT,
                   const float* __restrict__ keepP, float* __restrict__ ctx2)
{
    __shared__ char smem[53248];
    unsigned short* kst  = (unsigned short*)smem;            // [128][64]  16384 B
    unsigned short* vst  = (unsigned short*)(smem + 16384);  // [64][128]  16384 B
    unsigned short* Pall = (unsigned short*)(smem + 32768);  // 4 x [64][40] 20480 B
    float* redC  = (float*)smem;                             // overlay [64][66]
    float* red16 = (float*)(smem + 16896);                   // [16][64]
    float* dinv  = (float*)(smem + 20992);                   // [64]

    const int blk = blockIdx.x;
    const int ib = blk % NIB;
    const int bh = blk / NIB;
    const int b = bh / Hh, h = bh % Hh;
    const int tid = threadIdx.x;
    const int ws = tid >> 6;
    const int ln = tid & 63;
    const int i16 = ln & 15, q = ln >> 4;

    short8 Qf[4][2];
#pragma unroll
    for (int it = 0; it < 4; ++it)
#pragma unroll
        for (int kc = 0; kc < 2; ++kc)
            Qf[it][kc] = *(const short8*)&qB[(((size_t)bh * IT_TILES + ib * 4 + it) * 2 + kc) * 512 + ln * 8];

    float keepi[4];
#pragma unroll
    for (int it = 0; it < 4; ++it)
        keepi[it] = keepP[b * JP + (ib * 4 + it) * 16 + i16];

    floatx4 ctxacc[4][4];
#pragma unroll
    for (int it = 0; it < 4; ++it)
#pragma unroll
        for (int dt = 0; dt < 4; ++dt)
            ctxacc[it][dt] = (floatx4){0.f, 0.f, 0.f, 0.f};
    float dsacc[4] = {0.f, 0.f, 0.f, 0.f};

    unsigned short* Pw = Pall + ws * 2560;    // [64][40] bf16

    for (int sw = 0; sw < NSW; ++sw) {
        const int j0 = sw * 128;
        __syncthreads();
#pragma unroll
        for (int r = 0; r < 4; ++r) {
            int id = tid + 256 * r;
            int j = id >> 3, cc = id & 7;
            *(uint4*)&kst[j * 64 + ((cc ^ (j & 7)) * 8)] =
                *(const uint4*)&kR[((size_t)bh * JP + j0 + j) * 64 + cc * 8];
        }
#pragma unroll
        for (int r = 0; r < 4; ++r) {
            int id = tid + 256 * r;
            int d = id >> 4, c = id & 15;
            *(uint4*)&vst[d * 128 + ((c ^ (d & 15)) * 8)] =
                *(const uint4*)&vT[((size_t)bh * 64 + d) * JP + j0 + c * 8];
        }
        __syncthreads();

        short8 Kf[2][2];
#pragma unroll
        for (int jt = 0; jt < 2; ++jt)
#pragma unroll
            for (int kc = 0; kc < 2; ++kc) {
                int jloc = ws * 32 + jt * 16 + i16;
                Kf[jt][kc] = *(const short8*)&kst[jloc * 64 + (((kc * 4 + q) ^ (jloc & 7)) * 8)];
            }

        floatx4 S[4][2];
#pragma unroll
        for (int it = 0; it < 4; ++it)
#pragma unroll
            for (int jt = 0; jt < 2; ++jt) {
                S[it][jt] = (floatx4){0.f, 0.f, 0.f, 0.f};
#pragma unroll
                for (int kc = 0; kc < 2; ++kc)
                    S[it][jt] = __builtin_amdgcn_mfma_f32_16x16x32_bf16(Kf[jt][kc], Qf[it][kc], S[it][jt], 0, 0, 0);
            }

        // keepj + validity per (jt, r), shared across it
        float kjv[2][4], vld[2][4];
#pragma unroll
        for (int jt = 0; jt < 2; ++jt)
#pragma unroll
            for (int r = 0; r < 4; ++r) {
                int jj = j0 + ws * 32 + jt * 16 + q * 4 + r;
                vld[jt][r] = (jj < Nn) ? 1.f : 0.f;
                kjv[jt][r] = keepP[b * JP + jj];     // pad region is 0
            }

#pragma unroll
        for (int it = 0; it < 4; ++it) {
            bool rk = keepi[it] > 0.5f;
#pragma unroll
            for (int jt = 0; jt < 2; ++jt) {
                float p[4];
#pragma unroll
                for (int r = 0; r < 4; ++r) {
                    float w = rk ? vld[jt][r] : kjv[jt][r];
                    p[r] = __expf(S[it][jt][r]) * w;
                    dsacc[it] += p[r];
                }
                unsigned int lo = (unsigned)tbf(p[0]) | ((unsigned)tbf(p[1]) << 16);
                unsigned int hi = (unsigned)tbf(p[2]) | ((unsigned)tbf(p[3]) << 16);
                uint2 pk; pk.x = lo; pk.y = hi;
                *(uint2*)&Pw[(it * 16 + i16) * 40 + jt * 16 + q * 4] = pk;
            }
        }

        // PV (P region is wave-private; no barrier needed)
        short8 Pf[4], Vf[4];
#pragma unroll
        for (int it = 0; it < 4; ++it)
            Pf[it] = *(const short8*)&Pw[(it * 16 + i16) * 40 + q * 8];
#pragma unroll
        for (int dt = 0; dt < 4; ++dt) {
            int dl = dt * 16 + i16;
            Vf[dt] = *(const short8*)&vst[dl * 128 + (((ws * 4 + q) ^ (dl & 15)) * 8)];
        }
#pragma unroll
        for (int it = 0; it < 4; ++it)
#pragma unroll
            for (int dt = 0; dt < 4; ++dt)
                ctxacc[it][dt] = __builtin_amdgcn_mfma_f32_16x16x32_bf16(Pf[it], Vf[dt], ctxacc[it][dt], 0, 0, 0);
    }

    // denominator reduce
    __syncthreads();
#pragma unroll
    for (int it = 0; it < 4; ++it) red16[(ws * 4 + q) * 64 + it * 16 + i16] = dsacc[it];
    __syncthreads();
    if (tid < 64) {
        float s = 0.f;
#pragma unroll
        for (int t = 0; t < 16; ++t) s += red16[t * 64 + tid];
        dinv[tid] = 1.f / (s + 1e-8f);
    }
    // cross-wave ctx reduce into redC (overlays kst/vst, dead now)
    for (int w = 0; w < 4; ++w) {
        __syncthreads();
        if (ws == w) {
#pragma unroll
            for (int it = 0; it < 4; ++it)
#pragma unroll
                for (int dt = 0; dt < 4; ++dt)
#pragma unroll
                    for (int r = 0; r < 4; ++r) {
                        int i = it * 16 + q * 4 + r;
                        int d = dt * 16 + i16;
                        float v = ctxacc[it][dt][r];
                        redC[i * 66 + d] = (w == 0) ? v : (redC[i * 66 + d] + v);
                    }
        }
    }
    __syncthreads();
#pragma unroll
    for (int rep = 0; rep < 16; ++rep) {
        int idx = tid + rep * 256;
        int i = idx >> 6, d = idx & 63;
        int gi = ib * 64 + i;
        if (gi < Nn)
            ctx2[((size_t)(b * Nn + gi)) * Cc + h * 64 + d] = redC[i * 66 + d] * dinv[i];
    }
}

// ---------------------------------------------------------------------------
extern "C" void kernel_launch(void* const* d_in, const int* in_sizes, int n_in,
                              void* d_out, int out_size, void* d_ws, size_t ws_size,
                              hipStream_t stream) {
    const float* x     = (const float*)d_in[0];
    const float* ucb   = (const float*)d_in[1];
    const float* Wqkv  = (const float*)d_in[2];
    const float* Wproj = (const float*)d_in[3];
    const float* bproj = (const float*)d_in[4];
    const int*   counter = (const int*)d_in[5];

    unsigned short* qB = (unsigned short*)d_ws;      // 48*68*2*512      = 3,342,336
    unsigned short* kR = qB + 3342336;               // 48*1152*64       = 3,538,944
    unsigned short* vT = kR + 3538944;               // 3,538,944
    float* colsum_b = (float*)(vT + 3538944);        // 4*1152
    float* keepP    = colsum_b + 4608;               // 4*1152
    float* cnt      = keepP + 4608;                  // 1152
    float* ctx2     = cnt + 1152;                    // [B,N,C] 3,148,800

    float* out  = (float*)d_out;                     // [B,N,C]
    float* out2 = out + 3148800;                     // [H,N]

    // zero qB..cnt (20,881,920 B = 5,220,480 u32)
    zero_ws<<<dim3(2048), dim3(256), 0, stream>>>((unsigned int*)d_ws, 5220480);
    gemm_tiled<<<dim3(65, 36), dim3(16, 16), 0, stream>>>(
        x, Wqkv, M_ROWS, Cc, 3 * Cc, 0, qB, kR, vT, nullptr, nullptr);
    attn_colsum_mfma<<<dim3(BH * NIB), dim3(256), 0, stream>>>(qB, kR, colsum_b);
    ucb_topk<<<dim3(Bb), dim3(1024), 0, stream>>>(colsum_b, ucb, counter, keepP, cnt);
    write_delta<<<dim3(49), dim3(256), 0, stream>>>(cnt, out2);
    attn_ctx_mfma<<<dim3(BH * NIB), dim3(256), 0, stream>>>(qB, kR, vT, keepP, ctx2);
    gemm_tiled<<<dim3(65, 12), dim3(16, 16), 0, stream>>>(
        ctx2, Wproj, M_ROWS, Cc, Cc, 1, nullptr, nullptr, nullptr, out, bproj);
}

// Round 4
// 249.262 us; speedup vs baseline: 12.0664x; 2.0559x over previous
//
#include <hip/hip_runtime.h>
#include <hip/hip_bf16.h>
#include <math.h>

// Problem constants
#define Bb 4
#define Nn 1025
#define Cc 768
#define Hh 12
#define BH (Bb*Hh)          // 48
#define M_ROWS 4100
#define KSEL 256            // int(1024*0.25)
#define JP 1152             // padded j (9 sweeps x 128)
#define IT_TILES 68         // qB i-tiles of 16 (i < 1088)
#define NIB 17              // i-blocks of 64
#define NSW 9               // j-sweeps of 128
#define MT16 264            // padded M tiles of 16 (4224 rows)
#define KC24 24             // 768/32 k-chunks

typedef __attribute__((ext_vector_type(8))) short short8;
typedef __attribute__((ext_vector_type(4))) float floatx4;

static __device__ inline unsigned short f2bf(float v) {       // RNE
    __hip_bfloat16 b = __float2bfloat16(v);
    return *reinterpret_cast<unsigned short*>(&b);
}
static __device__ inline unsigned short tbf(float f) {        // truncate (fast)
    union { float f; unsigned u; } x; x.f = f;
    return (unsigned short)(x.u >> 16);
}

// async global->LDS, 16B per lane; lds dest must be wave-uniform base
static __device__ inline void async16(const unsigned short* g, unsigned short* l) {
    __builtin_amdgcn_global_load_lds(
        (const __attribute__((address_space(1))) unsigned int*)g,
        (__attribute__((address_space(3))) unsigned int*)l, 16, 0, 0);
}

// ---------------------------------------------------------------------------
__global__ void zero_ws(unsigned int* p, int n) {
    for (int i = blockIdx.x * 256 + threadIdx.x; i < n; i += gridDim.x * 256)
        p[i] = 0u;
}

// ---------------------------------------------------------------------------
// x [4100x768] fp32 -> xA bf16 in A-fragment order:
// slot s = ((kc*264 + mt)*64 + q*16 + ml), elems e=0..7 ; A[m=mt*16+ml][k=kc*32+q*8+e]
__global__ __launch_bounds__(256)
void cast_x(const float* __restrict__ x, unsigned short* __restrict__ xA) {
    int s = blockIdx.x * 256 + threadIdx.x;         // < 405504
    int ml = s & 15, q = (s >> 4) & 3;
    int t2 = s >> 6;
    int mt = t2 % MT16, kc = t2 / MT16;
    int m = mt * 16 + ml, k = kc * 32 + q * 8;
    uint4 pk = {0u, 0u, 0u, 0u};
    if (m < M_ROWS) {
        float4 a = *(const float4*)&x[(size_t)m * 768 + k];
        float4 b2 = *(const float4*)&x[(size_t)m * 768 + k + 4];
        pk.x = (unsigned)f2bf(a.x)  | ((unsigned)f2bf(a.y)  << 16);
        pk.y = (unsigned)f2bf(a.z)  | ((unsigned)f2bf(a.w)  << 16);
        pk.z = (unsigned)f2bf(b2.x) | ((unsigned)f2bf(b2.y) << 16);
        pk.w = (unsigned)f2bf(b2.z) | ((unsigned)f2bf(b2.w) << 16);
    }
    *(uint4*)&xA[(size_t)s * 8] = pk;
}

// W [768xN] fp32 -> B-fragment order: slot = ((kc*NT + nt)*64 + q*16 + nl),
// elems e ; B[k=kc*32+q*8+e][n=nt*16+nl]
__global__ __launch_bounds__(256)
void cast_w(const float* __restrict__ W, unsigned short* __restrict__ WB,
            int N, int NT) {
    int s = blockIdx.x * 256 + threadIdx.x;         // < 24*NT*64
    int nl = s & 15, q = (s >> 4) & 3;
    int t2 = s >> 6;
    int nt = t2 % NT, kc = t2 / NT;
    int n = nt * 16 + nl, k = kc * 32 + q * 8;
    unsigned hv[8];
#pragma unroll
    for (int e = 0; e < 8; ++e)
        hv[e] = f2bf(W[(size_t)(k + e) * N + n]);
    uint4 pk;
    pk.x = hv[0] | (hv[1] << 16);
    pk.y = hv[2] | (hv[3] << 16);
    pk.z = hv[4] | (hv[5] << 16);
    pk.w = hv[6] | (hv[7] << 16);
    *(uint4*)&WB[(size_t)s * 8] = pk;
}

// ---------------------------------------------------------------------------
// MFMA bf16 GEMM, 128x128 tile, 4 waves x (4x4 of 16x16x32), BK=32.
// mode 0: scatter bf16 into qB (frag layout, x0.125), kR, vT
// mode 1: fp32 out[M,768] = C + bias
__global__ __launch_bounds__(256, 2)
void gemm_mfma(const unsigned short* __restrict__ Af,
               const unsigned short* __restrict__ Bf,
               int Nt16, int mode,
               unsigned short* __restrict__ qB, unsigned short* __restrict__ kR,
               unsigned short* __restrict__ vT,
               float* __restrict__ outp, const float* __restrict__ bias)
{
    __shared__ __align__(16) unsigned short ldsA[4096];   // 8 KB: 8 m-tiles x 512
    __shared__ __align__(16) unsigned short ldsB[4096];   // 8 KB: 8 n-tiles x 512
    const int tid = threadIdx.x;
    const int ln = tid & 63, w = tid >> 6;
    const int wm = w >> 1, wn = w & 1;
    const int mb = blockIdx.x, nb = blockIdx.y;

    floatx4 acc[4][4];
#pragma unroll
    for (int mt = 0; mt < 4; ++mt)
#pragma unroll
        for (int nt = 0; nt < 4; ++nt)
            acc[mt][nt] = (floatx4){0.f, 0.f, 0.f, 0.f};

    for (int kc = 0; kc < KC24; ++kc) {
        const unsigned short* gA = Af + ((size_t)(kc * MT16 + mb * 8)) * 512;
        const unsigned short* gB = Bf + ((size_t)(kc * Nt16 + nb * 8)) * 512;
        // wave w stages slots [w*128, w*128+128) of each (16B/lane)
        async16(gA + (size_t)(w * 128 + ln) * 8,      &ldsA[w * 1024]);
        async16(gA + (size_t)(w * 128 + 64 + ln) * 8, &ldsA[w * 1024 + 512]);
        async16(gB + (size_t)(w * 128 + ln) * 8,      &ldsB[w * 1024]);
        async16(gB + (size_t)(w * 128 + 64 + ln) * 8, &ldsB[w * 1024 + 512]);
        __syncthreads();

        short8 Am[4], Bn[4];
#pragma unroll
        for (int mt = 0; mt < 4; ++mt)
            Am[mt] = *(const short8*)&ldsA[((wm * 4 + mt) * 64 + ln) * 8];
#pragma unroll
        for (int nt = 0; nt < 4; ++nt)
            Bn[nt] = *(const short8*)&ldsB[((wn * 4 + nt) * 64 + ln) * 8];
#pragma unroll
        for (int mt = 0; mt < 4; ++mt)
#pragma unroll
            for (int nt = 0; nt < 4; ++nt)
                acc[mt][nt] = __builtin_amdgcn_mfma_f32_16x16x32_bf16(
                    Am[mt], Bn[nt], acc[mt][nt], 0, 0, 0);
        __syncthreads();
    }

    const int q = ln >> 4, l15 = ln & 15;
    if (mode == 1) {
#pragma unroll
        for (int nt = 0; nt < 4; ++nt) {
            int gn = nb * 128 + wn * 64 + nt * 16 + l15;
            float bv = bias[gn];
#pragma unroll
            for (int mt = 0; mt < 4; ++mt) {
                int gmb = mb * 128 + wm * 64 + mt * 16 + q * 4;
#pragma unroll
                for (int r = 0; r < 4; ++r) {
                    int gm = gmb + r;
                    if (gm < M_ROWS)
                        outp[(size_t)gm * 768 + gn] = acc[mt][nt][r] + bv;
                }
            }
        }
    } else {
#pragma unroll
        for (int nt = 0; nt < 4; ++nt) {
            int gn = nb * 128 + wn * 64 + nt * 16 + l15;
            int s = (gn >= 1536) ? 2 : (gn >= 768 ? 1 : 0);
            int rr = gn - s * Cc;
            int h = rr >> 6, d = rr & 63;
#pragma unroll
            for (int mt = 0; mt < 4; ++mt) {
                int gmb = mb * 128 + wm * 64 + mt * 16 + q * 4;
#pragma unroll
                for (int r = 0; r < 4; ++r) {
                    int gm = gmb + r;
                    if (gm >= M_ROWS) continue;
                    int b = gm / Nn;
                    int n = gm - b * Nn;
                    int bh = b * Hh + h;
                    float val = acc[mt][nt][r];
                    if (s == 0) {
                        int idx = (((bh * IT_TILES + (n >> 4)) * 2 + (d >> 5)) * 512)
                                  + ((((d & 31) >> 3) * 16 + (n & 15)) * 8) + (d & 7);
                        qB[idx] = f2bf(val * 0.125f);
                    } else if (s == 1) {
                        kR[((size_t)bh * JP + n) * 64 + d] = f2bf(val);
                    } else {
                        vT[((size_t)bh * 64 + d) * JP + n] = f2bf(val);
                    }
                }
            }
        }
    }
}

// ---------------------------------------------------------------------------
// Pass A (MFMA): colsum_b[b][j] += sum_h sum_i exp(s_ij)/l_i
__global__ __launch_bounds__(256, 2)
void attn_colsum_mfma(const unsigned short* __restrict__ qB,
                      const unsigned short* __restrict__ kR,
                      float* __restrict__ colsum_b)
{
    __shared__ unsigned short kst[128 * 64];
    __shared__ float scratch[4][32][17];
    __shared__ float red16[16][64];
    __shared__ float linv[64];

    const int blk = blockIdx.x;
    const int ib = blk % NIB;
    const int bh = blk / NIB;
    const int b = bh / Hh;
    const int tid = threadIdx.x;
    const int ws = tid >> 6;
    const int ln = tid & 63;
    const int i16 = ln & 15, q = ln >> 4;

    short8 Qf[4][2];
#pragma unroll
    for (int it = 0; it < 4; ++it)
#pragma unroll
        for (int kc = 0; kc < 2; ++kc)
            Qf[it][kc] = *(const short8*)&qB[(((size_t)bh * IT_TILES + ib * 4 + it) * 2 + kc) * 512 + ln * 8];

    float lacc[4] = {0.f, 0.f, 0.f, 0.f};

    for (int sw = 0; sw < NSW; ++sw) {
        const int j0 = sw * 128;
        __syncthreads();
#pragma unroll
        for (int r = 0; r < 4; ++r) {
            int id = tid + 256 * r;
            int j = id >> 3, cc = id & 7;
            *(uint4*)&kst[j * 64 + ((cc ^ (j & 7)) * 8)] =
                *(const uint4*)&kR[((size_t)bh * JP + j0 + j) * 64 + cc * 8];
        }
        __syncthreads();

        short8 Kf[2][2];
#pragma unroll
        for (int jt = 0; jt < 2; ++jt)
#pragma unroll
            for (int kc = 0; kc < 2; ++kc) {
                int jloc = ws * 32 + jt * 16 + i16;
                Kf[jt][kc] = *(const short8*)&kst[jloc * 64 + (((kc * 4 + q) ^ (jloc & 7)) * 8)];
            }

        floatx4 S[4][2];
#pragma unroll
        for (int it = 0; it < 4; ++it)
#pragma unroll
            for (int jt = 0; jt < 2; ++jt) {
                S[it][jt] = (floatx4){0.f, 0.f, 0.f, 0.f};
#pragma unroll
                for (int kc = 0; kc < 2; ++kc)
                    S[it][jt] = __builtin_amdgcn_mfma_f32_16x16x32_bf16(Kf[jt][kc], Qf[it][kc], S[it][jt], 0, 0, 0);
            }

#pragma unroll
        for (int jt = 0; jt < 2; ++jt)
#pragma unroll
            for (int r = 0; r < 4; ++r) {
                int jj = j0 + ws * 32 + jt * 16 + q * 4 + r;
                float vld = (jj < Nn) ? 1.f : 0.f;
#pragma unroll
                for (int it = 0; it < 4; ++it)
                    lacc[it] += __expf(S[it][jt][r]) * vld;
            }
    }

    __syncthreads();
#pragma unroll
    for (int it = 0; it < 4; ++it) red16[ws * 4 + q][it * 16 + i16] = lacc[it];
    __syncthreads();
    if (tid < 64) {
        float s = 0.f;
#pragma unroll
        for (int t = 0; t < 16; ++t) s += red16[t][tid];
        int gi = ib * 64 + tid;
        linv[tid] = (gi < Nn) ? 1.f / s : 0.f;
    }
    __syncthreads();
    float lw[4];
#pragma unroll
    for (int it = 0; it < 4; ++it) lw[it] = linv[it * 16 + i16];

    for (int sw = 0; sw < NSW; ++sw) {
        const int j0 = sw * 128;
        __syncthreads();
#pragma unroll
        for (int r = 0; r < 4; ++r) {
            int id = tid + 256 * r;
            int j = id >> 3, cc = id & 7;
            *(uint4*)&kst[j * 64 + ((cc ^ (j & 7)) * 8)] =
                *(const uint4*)&kR[((size_t)bh * JP + j0 + j) * 64 + cc * 8];
        }
        __syncthreads();

        short8 Kf[2][2];
#pragma unroll
        for (int jt = 0; jt < 2; ++jt)
#pragma unroll
            for (int kc = 0; kc < 2; ++kc) {
                int jloc = ws * 32 + jt * 16 + i16;
                Kf[jt][kc] = *(const short8*)&kst[jloc * 64 + (((kc * 4 + q) ^ (jloc & 7)) * 8)];
            }

        floatx4 S[4][2];
#pragma unroll
        for (int it = 0; it < 4; ++it)
#pragma unroll
            for (int jt = 0; jt < 2; ++jt) {
                S[it][jt] = (floatx4){0.f, 0.f, 0.f, 0.f};
#pragma unroll
                for (int kc = 0; kc < 2; ++kc)
                    S[it][jt] = __builtin_amdgcn_mfma_f32_16x16x32_bf16(Kf[jt][kc], Qf[it][kc], S[it][jt], 0, 0, 0);
            }

        float pj[2][4];
#pragma unroll
        for (int jt = 0; jt < 2; ++jt)
#pragma unroll
            for (int r = 0; r < 4; ++r) {
                int jj = j0 + ws * 32 + jt * 16 + q * 4 + r;
                float vld = (jj < Nn) ? 1.f : 0.f;
                float s = 0.f;
#pragma unroll
                for (int it = 0; it < 4; ++it)
                    s += __expf(S[it][jt][r]) * lw[it];
                pj[jt][r] = s * vld;
            }
#pragma unroll
        for (int jt = 0; jt < 2; ++jt)
#pragma unroll
            for (int r = 0; r < 4; ++r)
                scratch[ws][jt * 16 + q * 4 + r][i16] = pj[jt][r];
        __syncthreads();
        if (tid < 128) {
            int wr = tid >> 5, jl = tid & 31;
            float s = 0.f;
#pragma unroll
            for (int t = 0; t < 16; ++t) s += scratch[wr][jl][t];
            atomicAdd(&colsum_b[b * JP + j0 + wr * 32 + jl], s);
        }
    }
}

// ---------------------------------------------------------------------------
__global__ __launch_bounds__(1024)
void ucb_topk(const float* __restrict__ colsum_b, const float* __restrict__ ucb_score,
              const int* __restrict__ counter_p,
              float* __restrict__ keepP, float* __restrict__ cnt)
{
    const int b = blockIdx.x;
    const int tid = threadIdx.x;
    __shared__ float vals[1024];
    __shared__ int   idxs[1024];

    const int j = tid + 1;
    float lc = logf((float)(*counter_p) + 1.0f);
    float s = colsum_b[b * JP + j] * (1.0f / (float)Nn);
#pragma unroll
    for (int h = 0; h < Hh; ++h)
        s += sqrtf(lc / (ucb_score[h * Nn + j] + 1e-6f));
    s *= (1.0f / (float)Hh);
    vals[tid] = s; idxs[tid] = tid;
    __syncthreads();

    for (int k = 2; k <= 1024; k <<= 1) {
        for (int jj = k >> 1; jj > 0; jj >>= 1) {
            int partner = tid ^ jj;
            if (partner > tid) {
                float v1 = vals[tid], v2 = vals[partner];
                int i1 = idxs[tid], i2 = idxs[partner];
                bool gt = (v1 > v2) || (v1 == v2 && i1 < i2);
                bool desc = ((tid & k) == 0);
                if (desc ? !gt : gt) {
                    vals[tid] = v2; vals[partner] = v1;
                    idxs[tid] = i2; idxs[partner] = i1;
                }
            }
            __syncthreads();
        }
    }

    if (tid < KSEL) {
        int tok = idxs[tid] + 1;
        keepP[b * JP + tok] = 1.f;
        atomicAdd(&cnt[tok], 1.0f / (float)Bb);
    }
    if (tid == 0) keepP[b * JP + 0] = 1.f;
}

// ---------------------------------------------------------------------------
__global__ void write_delta(const float* __restrict__ cnt, float* __restrict__ out2) {
    int t = blockIdx.x * 256 + threadIdx.x;
    if (t < Hh * Nn) out2[t] = cnt[t % Nn];
}

// ---------------------------------------------------------------------------
// Pass B (MFMA): masked renormalized context; writes ctxA in A-fragment bf16
// layout for the projection GEMM (M index m = b*Nn + token, K index = h*64+d).
__global__ __launch_bounds__(256, 2)
void attn_ctx_mfma(const unsigned short* __restrict__ qB,
                   const unsigned short* __restrict__ kR,
                   const unsigned short* __restrict__ vT,
                   const float* __restrict__ keepP, unsigned short* __restrict__ ctxA)
{
    __shared__ char smem[53248];
    unsigned short* kst  = (unsigned short*)smem;            // [128][64]  16384 B
    unsigned short* vst  = (unsigned short*)(smem + 16384);  // [64][128]  16384 B
    unsigned short* Pall = (unsigned short*)(smem + 32768);  // 4 x [64][40] 20480 B
    float* redC  = (float*)smem;                             // overlay [64][66]
    float* red16 = (float*)(smem + 16896);                   // [16][64]
    float* dinv  = (float*)(smem + 20992);                   // [64]

    const int blk = blockIdx.x;
    const int ib = blk % NIB;
    const int bh = blk / NIB;
    const int b = bh / Hh, h = bh % Hh;
    const int tid = threadIdx.x;
    const int ws = tid >> 6;
    const int ln = tid & 63;
    const int i16 = ln & 15, q = ln >> 4;

    short8 Qf[4][2];
#pragma unroll
    for (int it = 0; it < 4; ++it)
#pragma unroll
        for (int kc = 0; kc < 2; ++kc)
            Qf[it][kc] = *(const short8*)&qB[(((size_t)bh * IT_TILES + ib * 4 + it) * 2 + kc) * 512 + ln * 8];

    float keepi[4];
#pragma unroll
    for (int it = 0; it < 4; ++it)
        keepi[it] = keepP[b * JP + (ib * 4 + it) * 16 + i16];

    floatx4 ctxacc[4][4];
#pragma unroll
    for (int it = 0; it < 4; ++it)
#pragma unroll
        for (int dt = 0; dt < 4; ++dt)
            ctxacc[it][dt] = (floatx4){0.f, 0.f, 0.f, 0.f};
    float dsacc[4] = {0.f, 0.f, 0.f, 0.f};

    unsigned short* Pw = Pall + ws * 2560;

    for (int sw = 0; sw < NSW; ++sw) {
        const int j0 = sw * 128;
        __syncthreads();
#pragma unroll
        for (int r = 0; r < 4; ++r) {
            int id = tid + 256 * r;
            int j = id >> 3, cc = id & 7;
            *(uint4*)&kst[j * 64 + ((cc ^ (j & 7)) * 8)] =
                *(const uint4*)&kR[((size_t)bh * JP + j0 + j) * 64 + cc * 8];
        }
#pragma unroll
        for (int r = 0; r < 4; ++r) {
            int id = tid + 256 * r;
            int d = id >> 4, c = id & 15;
            *(uint4*)&vst[d * 128 + ((c ^ (d & 15)) * 8)] =
                *(const uint4*)&vT[((size_t)bh * 64 + d) * JP + j0 + c * 8];
        }
        __syncthreads();

        short8 Kf[2][2];
#pragma unroll
        for (int jt = 0; jt < 2; ++jt)
#pragma unroll
            for (int kc = 0; kc < 2; ++kc) {
                int jloc = ws * 32 + jt * 16 + i16;
                Kf[jt][kc] = *(const short8*)&kst[jloc * 64 + (((kc * 4 + q) ^ (jloc & 7)) * 8)];
            }

        floatx4 S[4][2];
#pragma unroll
        for (int it = 0; it < 4; ++it)
#pragma unroll
            for (int jt = 0; jt < 2; ++jt) {
                S[it][jt] = (floatx4){0.f, 0.f, 0.f, 0.f};
#pragma unroll
                for (int kc = 0; kc < 2; ++kc)
                    S[it][jt] = __builtin_amdgcn_mfma_f32_16x16x32_bf16(Kf[jt][kc], Qf[it][kc], S[it][jt], 0, 0, 0);
            }

        float kjv[2][4], vld[2][4];
#pragma unroll
        for (int jt = 0; jt < 2; ++jt)
#pragma unroll
            for (int r = 0; r < 4; ++r) {
                int jj = j0 + ws * 32 + jt * 16 + q * 4 + r;
                vld[jt][r] = (jj < Nn) ? 1.f : 0.f;
                kjv[jt][r] = keepP[b * JP + jj];
            }

#pragma unroll
        for (int it = 0; it < 4; ++it) {
            bool rk = keepi[it] > 0.5f;
#pragma unroll
            for (int jt = 0; jt < 2; ++jt) {
                float p[4];
#pragma unroll
                for (int r = 0; r < 4; ++r) {
                    float w = rk ? vld[jt][r] : kjv[jt][r];
                    p[r] = __expf(S[it][jt][r]) * w;
                    dsacc[it] += p[r];
                }
                unsigned int lo = (unsigned)tbf(p[0]) | ((unsigned)tbf(p[1]) << 16);
                unsigned int hi = (unsigned)tbf(p[2]) | ((unsigned)tbf(p[3]) << 16);
                uint2 pk; pk.x = lo; pk.y = hi;
                *(uint2*)&Pw[(it * 16 + i16) * 40 + jt * 16 + q * 4] = pk;
            }
        }

        short8 Pf[4], Vf[4];
#pragma unroll
        for (int it = 0; it < 4; ++it)
            Pf[it] = *(const short8*)&Pw[(it * 16 + i16) * 40 + q * 8];
#pragma unroll
        for (int dt = 0; dt < 4; ++dt) {
            int dl = dt * 16 + i16;
            Vf[dt] = *(const short8*)&vst[dl * 128 + (((ws * 4 + q) ^ (dl & 15)) * 8)];
        }
#pragma unroll
        for (int it = 0; it < 4; ++it)
#pragma unroll
            for (int dt = 0; dt < 4; ++dt)
                ctxacc[it][dt] = __builtin_amdgcn_mfma_f32_16x16x32_bf16(Pf[it], Vf[dt], ctxacc[it][dt], 0, 0, 0);
    }

    __syncthreads();
#pragma unroll
    for (int it = 0; it < 4; ++it) red16[(ws * 4 + q) * 64 + it * 16 + i16] = dsacc[it];
    __syncthreads();
    if (tid < 64) {
        float s = 0.f;
#pragma unroll
        for (int t = 0; t < 16; ++t) s += red16[t * 64 + tid];
        dinv[tid] = 1.f / (s + 1e-8f);
    }
    for (int w = 0; w < 4; ++w) {
        __syncthreads();
        if (ws == w) {
#pragma unroll
            for (int it = 0; it < 4; ++it)
#pragma unroll
                for (int dt = 0; dt < 4; ++dt)
#pragma unroll
                    for (int r = 0; r < 4; ++r) {
                        int i = it * 16 + q * 4 + r;
                        int d = dt * 16 + i16;
                        float v = ctxacc[it][dt][r];
                        redC[i * 66 + d] = (w == 0) ? v : (redC[i * 66 + d] + v);
                    }
        }
    }
    __syncthreads();
    // write ctxA in A-fragment order: m = b*Nn+gi, k = h*64+d
#pragma unroll
    for (int rep = 0; rep < 2; ++rep) {
        int s2 = tid + rep * 256;          // < 512 : i(6b) x dc(3b)
        int i = s2 >> 3, dc = s2 & 7;
        int gi = ib * 64 + i;
        if (gi < Nn) {
            int m = b * Nn + gi;
            float dv = dinv[i];
            const float* src = &redC[i * 66 + dc * 8];
            uint4 pk;
            pk.x = (unsigned)f2bf(src[0] * dv) | ((unsigned)f2bf(src[1] * dv) << 16);
            pk.y = (unsigned)f2bf(src[2] * dv) | ((unsigned)f2bf(src[3] * dv) << 16);
            pk.z = (unsigned)f2bf(src[4] * dv) | ((unsigned)f2bf(src[5] * dv) << 16);
            pk.w = (unsigned)f2bf(src[6] * dv) | ((unsigned)f2bf(src[7] * dv) << 16);
            int kc2 = h * 2 + (dc >> 2);
            int q2 = dc & 3;
            size_t idx = (((size_t)(kc2 * MT16 + (m >> 4))) * 64 + q2 * 16 + (m & 15)) * 8;
            *(uint4*)&ctxA[idx] = pk;
        }
    }
}

// ---------------------------------------------------------------------------
extern "C" void kernel_launch(void* const* d_in, const int* in_sizes, int n_in,
                              void* d_out, int out_size, void* d_ws, size_t ws_size,
                              hipStream_t stream) {
    const float* x     = (const float*)d_in[0];
    const float* ucb   = (const float*)d_in[1];
    const float* Wqkv  = (const float*)d_in[2];
    const float* Wproj = (const float*)d_in[3];
    const float* bproj = (const float*)d_in[4];
    const int*   counter = (const int*)d_in[5];

    unsigned short* qB = (unsigned short*)d_ws;      // 3,342,336 sh
    unsigned short* kR = qB + 3342336;               // 3,538,944 sh
    unsigned short* vT = kR + 3538944;               // 3,538,944 sh
    float* colsum_b = (float*)(vT + 3538944);        // 4608 f
    float* keepP    = colsum_b + 4608;               // 4608 f
    float* cnt      = keepP + 4608;                  // 1152 f
    unsigned short* ctxA = (unsigned short*)(cnt + 1152);  // 24*264*512 = 3,244,032 sh
    unsigned short* xA   = ctxA + 3244032;           // 3,244,032 sh
    unsigned short* WB   = xA + 3244032;             // 24*144*512 = 1,769,472 sh
    unsigned short* WpB  = WB + 1769472;             // 24*48*512  =   589,824 sh

    float* out  = (float*)d_out;                     // [B,N,C]
    float* out2 = out + 3148800;                     // [H,N]

    // zero qB..cnt (pads must be 0): 20,881,920 B = 5,220,480 u32
    zero_ws<<<dim3(2048), dim3(256), 0, stream>>>((unsigned int*)d_ws, 5220480);
    cast_x<<<dim3(1584), dim3(256), 0, stream>>>(x, xA);
    cast_w<<<dim3(864), dim3(256), 0, stream>>>(Wqkv, WB, 2304, 144);
    cast_w<<<dim3(288), dim3(256), 0, stream>>>(Wproj, WpB, 768, 48);

    gemm_mfma<<<dim3(33, 18), dim3(256), 0, stream>>>(
        xA, WB, 144, 0, qB, kR, vT, nullptr, nullptr);
    attn_colsum_mfma<<<dim3(BH * NIB), dim3(256), 0, stream>>>(qB, kR, colsum_b);
    ucb_topk<<<dim3(Bb), dim3(1024), 0, stream>>>(colsum_b, ucb, counter, keepP, cnt);
    write_delta<<<dim3(49), dim3(256), 0, stream>>>(cnt, out2);
    attn_ctx_mfma<<<dim3(BH * NIB), dim3(256), 0, stream>>>(qB, kR, vT, keepP, ctxA);
    gemm_mfma<<<dim3(33, 6), dim3(256), 0, stream>>>(
        ctxA, WpB, 48, 1, nullptr, nullptr, nullptr, out, bproj);
}